// Round 6
// baseline (2009.339 us; speedup 1.0000x reference)
//
#include <hip/hip_runtime.h>

typedef unsigned short u16;
typedef __attribute__((ext_vector_type(8))) short bf16x8;
typedef __attribute__((ext_vector_type(4))) short bf16x4;
typedef __attribute__((ext_vector_type(4))) float f32x4;

#define MFMA16(a, b, c) __builtin_amdgcn_mfma_f32_16x16x32_bf16((a), (b), (c), 0, 0, 0)

// workspace layout (u16 element offsets)
#define OFF_UPAD 0
#define OFF_KS0  589824
#define OFF_W0   851968
#define OFF_W1   983040
#define OFF_W2   1114112
#define OFF_CRT  1179648
#define OFF_P    1196032     // 65 x 65536 (A^t, t=0..64, row-major, bf16)
#define OS_OFF   134479872   // 513*1024*256

__device__ __forceinline__ u16 f2bf(float f) {
  union { float f; unsigned int i; } v; v.f = f;
  return (u16)((v.i + 0x7fffu + ((v.i >> 16) & 1u)) >> 16);
}
__device__ __forceinline__ float bf2f(u16 u) {
  union { unsigned int i; float f; } v; v.i = ((unsigned int)u) << 16;
  return v.f;
}
__device__ __forceinline__ float fast_tanh(float x) {
  float e = __expf(2.0f * x);
  return 1.0f - __fdividef(2.0f, e + 1.0f);
}

// ---------------- prep: bf16 conversions + P0/P1 ----------------
__global__ void k_prep(const float* __restrict__ KS_ALL, const float* __restrict__ next_vf,
                       const float* __restrict__ A_w, const float* __restrict__ W0,
                       const float* __restrict__ W1, const float* __restrict__ W2,
                       u16* __restrict__ ws) {
  int idx = blockIdx.x * 256 + threadIdx.x;
  if (idx < 589824) {  // u_pad[1024][576]
    int r = idx / 576, c = idx % 576;
    ws[OFF_UPAD + idx] = (c < 64) ? (u16)0 : f2bf(next_vf[r * 512 + c - 64]);
    return;
  }
  idx -= 589824;
  if (idx < 262144) { ws[OFF_KS0 + idx] = f2bf(KS_ALL[idx]); return; }
  idx -= 262144;
  if (idx < 131072) { ws[OFF_W0 + idx] = f2bf(W0[idx]); return; }
  idx -= 131072;
  if (idx < 131072) { ws[OFF_W1 + idx] = f2bf(W1[idx]); return; }
  idx -= 131072;
  if (idx < 65536)  { ws[OFF_W2 + idx] = f2bf(W2[idx]); return; }
  idx -= 65536;
  if (idx < 65536) { // P0 = I, P1 = A
    int r = idx >> 8, c = idx & 255;
    ws[OFF_P + idx] = (r == c) ? (u16)0x3F80 : (u16)0;
    ws[OFF_P + 65536 + idx] = f2bf(A_w[idx]);
  }
}

// ---------------- power doubling ----------------
__global__ __launch_bounds__(512) void k_pow(u16* __restrict__ ws, int s) {
  const u16* P = ws + OFF_P;
  int j = blockIdx.y + 1;
  int mh = blockIdx.x;
  int lane = threadIdx.x & 63, w = threadIdx.x >> 6;
  int wm = w >> 2, wn = w & 3;
  int lg = lane >> 4, ll = lane & 15;
  const u16* Am = P + s * 65536;
  const u16* Bm = P + j * 65536;
  f32x4 acc[4][4];
  f32x4 z = {0.f, 0.f, 0.f, 0.f};
#pragma unroll
  for (int mi = 0; mi < 4; ++mi)
#pragma unroll
    for (int ni = 0; ni < 4; ++ni) acc[mi][ni] = z;
#pragma unroll
  for (int ks = 0; ks < 8; ++ks) {
    bf16x8 a[4], b[4];
    int kk = ks * 32 + lg * 8;
#pragma unroll
    for (int mi = 0; mi < 4; ++mi) {
      int row = mh * 128 + wm * 64 + mi * 16 + ll;
      a[mi] = *(const bf16x8*)(Am + row * 256 + kk);
    }
#pragma unroll
    for (int ni = 0; ni < 4; ++ni) {
      int col = wn * 64 + ni * 16 + ll;
#pragma unroll
      for (int e = 0; e < 8; ++e) b[ni][e] = (short)Bm[(kk + e) * 256 + col];
    }
#pragma unroll
    for (int mi = 0; mi < 4; ++mi)
#pragma unroll
      for (int ni = 0; ni < 4; ++ni) acc[mi][ni] = MFMA16(a[mi], b[ni], acc[mi][ni]);
  }
  u16* Pd = ws + OFF_P + (s + j) * 65536;
#pragma unroll
  for (int mi = 0; mi < 4; ++mi)
#pragma unroll
    for (int ni = 0; ni < 4; ++ni)
#pragma unroll
      for (int r = 0; r < 4; ++r) {
        int row = mh * 128 + wm * 64 + mi * 16 + lg * 4 + r;
        int col = wn * 64 + ni * 16 + ll;
        Pd[row * 256 + col] = f2bf(acc[mi][ni][r]);
      }
}

// ---------------- CrevT[n][s] = c_{63-s}[n] ----------------
__global__ void k_crevt(const float* __restrict__ B_w, u16* __restrict__ ws) {
  int s = blockIdx.x;
  int n = threadIdx.x;
  const u16* Pr = ws + OFF_P + (63 - s) * 65536 + n * 256;
  float acc = 0.f;
  for (int k = 0; k < 256; ++k) acc += bf2f(Pr[k]) * B_w[k];
  ws[OFF_CRT + n * 64 + s] = f2bf(acc);
}

// ---------------- fused KS-gen + MLP: BM=32, 512 thr, 8 waves ----------------
// NO launch-bounds min arg: observed (512,>=2) -> 64-VGPR cap -> spills.
// LDS 59.4 KB -> 2 blocks/CU; VGPR ~128 -> 4 waves/SIMD. Phase-1 f32 acc kept
// in registers through L1/L2 so residual + LN input are computed in f32.
__global__ __launch_bounds__(512) void k_fused(
    const u16* __restrict__ ws,
    const float* __restrict__ b0, const float* __restrict__ b1,
    const float* __restrict__ lng, const float* __restrict__ lnb,
    const float* __restrict__ b2, const float* __restrict__ W3,
    const float* __restrict__ b3, float* __restrict__ out) {
  // Xb: [32][256] bf16 XOR-swz (512B stride): X for L1; later LN-out for L3.
  __shared__ __align__(16) u16 Xb[8448];
  // Hraw: f32 bounce [32][260] (33.3KB) / H1 [32][512] swz (32KB) / LN-in f32 [32][260] / elu [32][264] u16
  __shared__ __align__(16) unsigned char Hraw[33280];
  __shared__ float par[2308];
  u16* Hb = (u16*)Hraw;
  float* Hf = (float*)Hraw;

  float* pb0 = par;          // 512
  float* pb1 = par + 512;    // 256
  float* pg  = par + 768;    // 256
  float* pbt = par + 1024;   // 256
  float* pb2 = par + 1280;   // 256
  float* pW3 = par + 1536;   // 768
  float* pb3 = par + 2304;   // 4

  const int t  = blockIdx.y;        // 0..512
  const int R0 = blockIdx.x * 32;   // row base
  const int tid = threadIdx.x;
  const int lane = tid & 63, w = tid >> 6;
  const int lg = lane >> 4, ll = lane & 15;

  pb0[tid] = b0[tid];
  if (tid < 256) { pb1[tid] = b1[tid]; pg[tid] = lng[tid]; pbt[tid] = lnb[tid]; pb2[tid] = b2[tid]; }
  if (tid < 512) pW3[tid] = W3[tid];
  if (tid < 256) pW3[512 + tid] = W3[512 + tid];
  if (tid < 4) pb3[tid] = (tid < 3) ? b3[tid] : 0.f;

  f32x4 z = {0.f, 0.f, 0.f, 0.f};

  // ---- phase 1: KS_pre rows R0..R0+31; wave w -> cols w*32..+31; accP[2][2] LIVE ----
  f32x4 accP[2][2];
#pragma unroll
  for (int mi = 0; mi < 2; ++mi)
#pragma unroll
    for (int ni = 0; ni < 2; ++ni) accP[mi][ni] = z;
  {
    const u16* CrevT = ws + OFF_CRT;
    bf16x8 au[2][2];
#pragma unroll
    for (int mi = 0; mi < 2; ++mi)
#pragma unroll
      for (int ksu = 0; ksu < 2; ++ksu) {
        const u16* up = ws + OFF_UPAD + (R0 + mi * 16 + ll) * 576 + t + ksu * 32 + lg * 8;
#pragma unroll
        for (int e = 0; e < 8; ++e) au[mi][ksu][e] = (short)up[e];
      }
#pragma unroll
    for (int ksu = 0; ksu < 2; ++ksu)
#pragma unroll
      for (int ni = 0; ni < 2; ++ni) {
        int n = w * 32 + ni * 16 + ll;
        bf16x8 bfr = *(const bf16x8*)(CrevT + n * 64 + ksu * 32 + lg * 8);
#pragma unroll
        for (int mi = 0; mi < 2; ++mi) accP[mi][ni] = MFMA16(au[mi][ksu], bfr, accP[mi][ni]);
      }
    if (t < 64) {
      const u16* Pt = ws + OFF_P + t * 65536;
      const u16* ks0b = ws + OFF_KS0;
#pragma unroll
      for (int ks = 0; ks < 8; ++ks) {
        bf16x8 a[2], b[2];
#pragma unroll
        for (int mi = 0; mi < 2; ++mi)
          a[mi] = *(const bf16x8*)(ks0b + (R0 + mi * 16 + ll) * 256 + ks * 32 + lg * 8);
#pragma unroll
        for (int ni = 0; ni < 2; ++ni)
          b[ni] = *(const bf16x8*)(Pt + (w * 32 + ni * 16 + ll) * 256 + ks * 32 + lg * 8);
#pragma unroll
        for (int mi = 0; mi < 2; ++mi)
#pragma unroll
          for (int ni = 0; ni < 2; ++ni) accP[mi][ni] = MFMA16(a[mi], b[ni], accP[mi][ni]);
      }
    }
  }

  // ---- KS store via f32 bounce [32][260], single pass; Xb (bf16 swz) built alongside ----
#pragma unroll
  for (int mi = 0; mi < 2; ++mi)
#pragma unroll
    for (int ni = 0; ni < 2; ++ni)
#pragma unroll
      for (int r = 0; r < 4; ++r)
        Hf[(mi * 16 + lg * 4 + r) * 260 + w * 32 + ni * 16 + ll] = accP[mi][ni][r];
  __syncthreads();
  {
    float* ob = out + (size_t)t * 262144 + (size_t)R0 * 256;
#pragma unroll
    for (int it = 0; it < 4; ++it) {
      int idx = it * 512 + tid;
      int row = idx >> 6, c4 = idx & 63;
      f32x4 v = *(const f32x4*)(Hf + row * 260 + c4 * 4);
      *(f32x4*)(ob + row * 256 + c4 * 4) = v;
      bf16x4 h;
#pragma unroll
      for (int e = 0; e < 4; ++e) h[e] = (short)f2bf(v[e]);
      int byt = (((row << 9) + ((c4 >> 1) << 4)) ^ ((row & 7) << 4)) + ((c4 & 1) << 3);
      *(bf16x4*)(Xb + (byt >> 1)) = h;
    }
  }
  __syncthreads();  // Hf reads done; Hraw becomes H1

  // ---- L1: H1 = tanh(X @ W0^T + b0); out 32x512, wave tile 32x64; accA[2][4] ----
  {
    const u16* W0b = ws + OFF_W0;
    f32x4 accA[2][4];
#pragma unroll
    for (int mi = 0; mi < 2; ++mi)
#pragma unroll
      for (int ni = 0; ni < 4; ++ni) accA[mi][ni] = z;
#pragma unroll
    for (int ks = 0; ks < 8; ++ks) {
      bf16x8 a[2], b[4];
#pragma unroll
      for (int mi = 0; mi < 2; ++mi) {
        int rl = mi * 16 + ll;
        int byt = ((rl << 9) + ks * 64 + (lg << 4)) ^ ((rl & 7) << 4);
        a[mi] = *(const bf16x8*)(Xb + (byt >> 1));
      }
#pragma unroll
      for (int ni = 0; ni < 4; ++ni) {
        int n = w * 64 + ni * 16 + ll;
        b[ni] = *(const bf16x8*)(W0b + n * 256 + ks * 32 + lg * 8);
      }
#pragma unroll
      for (int mi = 0; mi < 2; ++mi)
#pragma unroll
        for (int ni = 0; ni < 4; ++ni) accA[mi][ni] = MFMA16(a[mi], b[ni], accA[mi][ni]);
    }
    // tanh -> H1 [32][512] swz (1024B stride)
#pragma unroll
    for (int mi = 0; mi < 2; ++mi)
#pragma unroll
      for (int ni = 0; ni < 4; ++ni)
#pragma unroll
        for (int r = 0; r < 4; ++r) {
          int rl = mi * 16 + lg * 4 + r;
          int col = w * 64 + ni * 16 + ll;
          float v = fast_tanh(accA[mi][ni][r] + pb0[col]);
          int byt = ((rl << 10) + (col << 1)) ^ ((rl & 7) << 4);
          Hb[byt >> 1] = f2bf(v);
        }
  }
  __syncthreads();

  // ---- L2: accL2 = H1 @ W1^T (K=512); out 32x256, wave tile 32x32 ----
  f32x4 accL2[2][2];
#pragma unroll
  for (int mi = 0; mi < 2; ++mi)
#pragma unroll
    for (int ni = 0; ni < 2; ++ni) accL2[mi][ni] = z;
  {
    const u16* W1b = ws + OFF_W1;
#pragma unroll
    for (int ks = 0; ks < 16; ++ks) {
      bf16x8 a[2], b[2];
#pragma unroll
      for (int mi = 0; mi < 2; ++mi) {
        int rl = mi * 16 + ll;
        int byt = ((rl << 10) + ks * 64 + (lg << 4)) ^ ((rl & 7) << 4);
        a[mi] = *(const bf16x8*)(Hb + (byt >> 1));
      }
#pragma unroll
      for (int ni = 0; ni < 2; ++ni) {
        int n = w * 32 + ni * 16 + ll;
        b[ni] = *(const bf16x8*)(W1b + n * 512 + ks * 32 + lg * 8);
      }
#pragma unroll
      for (int mi = 0; mi < 2; ++mi)
#pragma unroll
        for (int ni = 0; ni < 2; ++ni) accL2[mi][ni] = MFMA16(a[mi], b[ni], accL2[mi][ni]);
    }
  }
  __syncthreads();  // H1 reads done; Hraw becomes f32 LN-input

  // ---- residual in f32: r = accP + tanh(accL2 + b1) -> Hf [32][260] ----
#pragma unroll
  for (int mi = 0; mi < 2; ++mi)
#pragma unroll
    for (int ni = 0; ni < 2; ++ni)
#pragma unroll
      for (int r = 0; r < 4; ++r) {
        int rl = mi * 16 + lg * 4 + r;
        int col = w * 32 + ni * 16 + ll;
        float v = accP[mi][ni][r] + fast_tanh(accL2[mi][ni][r] + pb1[col]);
        Hf[rl * 260 + col] = v;
      }
  __syncthreads();

  // ---- LayerNorm per row on f32; write bf16 -> Xb swz; 16 lanes per row ----
  {
    int row = tid >> 4, jq = tid & 15;
    const float* hr = Hf + row * 260 + jq * 16;
    f32x4 cf[4];
#pragma unroll
    for (int q = 0; q < 4; ++q) cf[q] = *(const f32x4*)(hr + q * 4);
    float s = 0.f, ss = 0.f;
#pragma unroll
    for (int q = 0; q < 4; ++q)
#pragma unroll
      for (int e = 0; e < 4; ++e) { float v = cf[q][e]; s += v; ss += v * v; }
    s += __shfl_xor(s, 1);  s += __shfl_xor(s, 2);  s += __shfl_xor(s, 4);  s += __shfl_xor(s, 8);
    ss += __shfl_xor(ss, 1); ss += __shfl_xor(ss, 2); ss += __shfl_xor(ss, 4); ss += __shfl_xor(ss, 8);
    float mu = s * 0.00390625f;
    float var = ss * 0.00390625f - mu * mu;
    float rstd = rsqrtf(var + 1e-5f);
#pragma unroll
    for (int q = 0; q < 2; ++q) {
      bf16x8 o;
#pragma unroll
      for (int e = 0; e < 8; ++e) {
        int e2 = q * 8 + e;
        int col = jq * 16 + e2;
        float v = (cf[e2 >> 2][e2 & 3] - mu) * rstd * pg[col] + pbt[col];
        o[e] = (short)f2bf(v);
      }
      int byt = ((row << 9) + ((jq * 16 + q * 8) << 1)) ^ ((row & 7) << 4);
      *(bf16x8*)(Xb + (byt >> 1)) = o;
    }
  }
  __syncthreads();

  // ---- L3: elu(s2n @ W2^T + b2) -> Hb [32][264] u16 ----
  f32x4 acc3[2][2];
#pragma unroll
  for (int mi = 0; mi < 2; ++mi)
#pragma unroll
    for (int ni = 0; ni < 2; ++ni) acc3[mi][ni] = z;
  {
    const u16* W2b = ws + OFF_W2;
#pragma unroll
    for (int ks = 0; ks < 8; ++ks) {
      bf16x8 a[2], b[2];
#pragma unroll
      for (int mi = 0; mi < 2; ++mi) {
        int rl = mi * 16 + ll;
        int byt = ((rl << 9) + ks * 64 + (lg << 4)) ^ ((rl & 7) << 4);
        a[mi] = *(const bf16x8*)(Xb + (byt >> 1));
      }
#pragma unroll
      for (int ni = 0; ni < 2; ++ni) {
        int n = w * 32 + ni * 16 + ll;
        b[ni] = *(const bf16x8*)(W2b + n * 256 + ks * 32 + lg * 8);
      }
#pragma unroll
      for (int mi = 0; mi < 2; ++mi)
#pragma unroll
        for (int ni = 0; ni < 2; ++ni) acc3[mi][ni] = MFMA16(a[mi], b[ni], acc3[mi][ni]);
    }
  }
#pragma unroll
  for (int mi = 0; mi < 2; ++mi)
#pragma unroll
    for (int ni = 0; ni < 2; ++ni)
#pragma unroll
      for (int r = 0; r < 4; ++r) {
        int rl = mi * 16 + lg * 4 + r;
        int col = w * 32 + ni * 16 + ll;
        float v = acc3[mi][ni][r] + pb2[col];
        v = v > 0.f ? v : (__expf(v) - 1.f);
        Hb[rl * 264 + col] = f2bf(v);
      }
  __syncthreads();

  // ---- OS = H3 @ W3^T + b3 ; 16 lanes per row ----
  {
    int row = tid >> 4, jq = tid & 15;
    const u16* xr = Hb + row * 264 + jq * 16;
    float d0 = 0.f, d1 = 0.f, d2 = 0.f;
#pragma unroll
    for (int q = 0; q < 2; ++q) {
      bf16x8 c = *(const bf16x8*)(xr + q * 8);
#pragma unroll
      for (int e = 0; e < 8; ++e) {
        float v = bf2f((u16)c[e]);
        int col = jq * 16 + q * 8 + e;
        d0 += v * pW3[col]; d1 += v * pW3[256 + col]; d2 += v * pW3[512 + col];
      }
    }
    d0 += __shfl_xor(d0, 1); d0 += __shfl_xor(d0, 2); d0 += __shfl_xor(d0, 4); d0 += __shfl_xor(d0, 8);
    d1 += __shfl_xor(d1, 1); d1 += __shfl_xor(d1, 2); d1 += __shfl_xor(d1, 4); d1 += __shfl_xor(d1, 8);
    d2 += __shfl_xor(d2, 1); d2 += __shfl_xor(d2, 2); d2 += __shfl_xor(d2, 4); d2 += __shfl_xor(d2, 8);
    if (jq == 0) {
      int grow = R0 + row;
      int ob = OS_OFF + t * 3072 + grow * 3;
      out[ob]     = d0 + pb3[0];
      out[ob + 1] = d1 + pb3[1];
      out[ob + 2] = d2 + pb3[2];
    }
  }
}

extern "C" void kernel_launch(void* const* d_in, const int* in_sizes, int n_in,
                              void* d_out, int out_size, void* d_ws, size_t ws_size,
                              hipStream_t stream) {
  const float* KS_ALL  = (const float*)d_in[0];
  const float* next_vf = (const float*)d_in[1];
  const float* A_w     = (const float*)d_in[2];
  const float* B_w     = (const float*)d_in[3];
  const float* W0      = (const float*)d_in[4];
  const float* b0      = (const float*)d_in[5];
  const float* W1      = (const float*)d_in[6];
  const float* b1      = (const float*)d_in[7];
  const float* lng     = (const float*)d_in[8];
  const float* lnb     = (const float*)d_in[9];
  const float* W2      = (const float*)d_in[10];
  const float* b2      = (const float*)d_in[11];
  const float* W3      = (const float*)d_in[12];
  const float* b3      = (const float*)d_in[13];
  u16* ws = (u16*)d_ws;
  float* out = (float*)d_out;

  k_prep<<<4864, 256, 0, stream>>>(KS_ALL, next_vf, A_w, W0, W1, W2, ws);
  for (int s = 1; s <= 32; s <<= 1)
    k_pow<<<dim3(2, s), 512, 0, stream>>>(ws, s);
  k_crevt<<<64, 256, 0, stream>>>(B_w, ws);
  k_fused<<<dim3(32, 513), 512, 0, stream>>>(ws, b0, b1, lng, lnb, b2, W3, b3, out);
}

// Round 7
// 1626.099 us; speedup vs baseline: 1.2357x; 1.2357x over previous
//
#include <hip/hip_runtime.h>

typedef unsigned short u16;
typedef __attribute__((ext_vector_type(8))) short bf16x8;
typedef __attribute__((ext_vector_type(4))) short bf16x4;
typedef __attribute__((ext_vector_type(4))) float f32x4;

#define MFMA16(a, b, c) __builtin_amdgcn_mfma_f32_16x16x32_bf16((a), (b), (c), 0, 0, 0)

// workspace layout (u16 element offsets)
#define OFF_UPAD 0
#define OFF_KS0  589824
#define OFF_W0   851968
#define OFF_W1   983040
#define OFF_W2   1114112
#define OFF_CRT  1179648
#define OFF_P    1196032     // 65 x 65536 (A^t, t=0..64, row-major, bf16)
#define OS_OFF   134479872   // 513*1024*256

__device__ __forceinline__ u16 f2bf(float f) {
  union { float f; unsigned int i; } v; v.f = f;
  return (u16)((v.i + 0x7fffu + ((v.i >> 16) & 1u)) >> 16);
}
__device__ __forceinline__ float bf2f(u16 u) {
  union { unsigned int i; float f; } v; v.i = ((unsigned int)u) << 16;
  return v.f;
}
__device__ __forceinline__ float fast_tanh(float x) {
  float e = __expf(2.0f * x);
  return 1.0f - __fdividef(2.0f, e + 1.0f);
}

// ---------------- prep: bf16 conversions + P0/P1 ----------------
__global__ void k_prep(const float* __restrict__ KS_ALL, const float* __restrict__ next_vf,
                       const float* __restrict__ A_w, const float* __restrict__ W0,
                       const float* __restrict__ W1, const float* __restrict__ W2,
                       u16* __restrict__ ws) {
  int idx = blockIdx.x * 256 + threadIdx.x;
  if (idx < 589824) {  // u_pad[1024][576]
    int r = idx / 576, c = idx % 576;
    ws[OFF_UPAD + idx] = (c < 64) ? (u16)0 : f2bf(next_vf[r * 512 + c - 64]);
    return;
  }
  idx -= 589824;
  if (idx < 262144) { ws[OFF_KS0 + idx] = f2bf(KS_ALL[idx]); return; }
  idx -= 262144;
  if (idx < 131072) { ws[OFF_W0 + idx] = f2bf(W0[idx]); return; }
  idx -= 131072;
  if (idx < 131072) { ws[OFF_W1 + idx] = f2bf(W1[idx]); return; }
  idx -= 131072;
  if (idx < 65536)  { ws[OFF_W2 + idx] = f2bf(W2[idx]); return; }
  idx -= 65536;
  if (idx < 65536) { // P0 = I, P1 = A
    int r = idx >> 8, c = idx & 255;
    ws[OFF_P + idx] = (r == c) ? (u16)0x3F80 : (u16)0;
    ws[OFF_P + 65536 + idx] = f2bf(A_w[idx]);
  }
}

// ---------------- power doubling ----------------
__global__ __launch_bounds__(512) void k_pow(u16* __restrict__ ws, int s) {
  const u16* P = ws + OFF_P;
  int j = blockIdx.y + 1;
  int mh = blockIdx.x;
  int lane = threadIdx.x & 63, w = threadIdx.x >> 6;
  int wm = w >> 2, wn = w & 3;
  int lg = lane >> 4, ll = lane & 15;
  const u16* Am = P + s * 65536;
  const u16* Bm = P + j * 65536;
  f32x4 acc[4][4];
  f32x4 z = {0.f, 0.f, 0.f, 0.f};
#pragma unroll
  for (int mi = 0; mi < 4; ++mi)
#pragma unroll
    for (int ni = 0; ni < 4; ++ni) acc[mi][ni] = z;
#pragma unroll
  for (int ks = 0; ks < 8; ++ks) {
    bf16x8 a[4], b[4];
    int kk = ks * 32 + lg * 8;
#pragma unroll
    for (int mi = 0; mi < 4; ++mi) {
      int row = mh * 128 + wm * 64 + mi * 16 + ll;
      a[mi] = *(const bf16x8*)(Am + row * 256 + kk);
    }
#pragma unroll
    for (int ni = 0; ni < 4; ++ni) {
      int col = wn * 64 + ni * 16 + ll;
#pragma unroll
      for (int e = 0; e < 8; ++e) b[ni][e] = (short)Bm[(kk + e) * 256 + col];
    }
#pragma unroll
    for (int mi = 0; mi < 4; ++mi)
#pragma unroll
      for (int ni = 0; ni < 4; ++ni) acc[mi][ni] = MFMA16(a[mi], b[ni], acc[mi][ni]);
  }
  u16* Pd = ws + OFF_P + (s + j) * 65536;
#pragma unroll
  for (int mi = 0; mi < 4; ++mi)
#pragma unroll
    for (int ni = 0; ni < 4; ++ni)
#pragma unroll
      for (int r = 0; r < 4; ++r) {
        int row = mh * 128 + wm * 64 + mi * 16 + lg * 4 + r;
        int col = wn * 64 + ni * 16 + ll;
        Pd[row * 256 + col] = f2bf(acc[mi][ni][r]);
      }
}

// ---------------- CrevT[n][s] = c_{63-s}[n] ----------------
__global__ void k_crevt(const float* __restrict__ B_w, u16* __restrict__ ws) {
  int s = blockIdx.x;
  int n = threadIdx.x;
  const u16* Pr = ws + OFF_P + (63 - s) * 65536 + n * 256;
  float acc = 0.f;
  for (int k = 0; k < 256; ++k) acc += bf2f(Pr[k]) * B_w[k];
  ws[OFF_CRT + n * 64 + s] = f2bf(acc);
}

// ---------------- fused KS-gen + MLP: BM=64, 512 thr, 8 waves, 2 blocks/CU ----------------
// NO __launch_bounds__ min arg (ledger: any arg>=2 -> 64-VGPR cap -> spills;
// plain (512) -> 128 VGPR, no spill). LDS 76.8 KB -> 2 blocks/CU by LDS;
// VGPR 128 -> 4 waves/SIMD. Cross-block phase desync hides L2/LDS latency.
__global__ __launch_bounds__(512) void k_fused(
    const u16* __restrict__ ws,
    const float* __restrict__ b0, const float* __restrict__ b1,
    const float* __restrict__ lng, const float* __restrict__ lnb,
    const float* __restrict__ b2, const float* __restrict__ W3,
    const float* __restrict__ b3, float* __restrict__ out) {
  // Xb usage A: [64][256] bf16 XOR-swz (512B stride): X for L1 + residual
  // Xb usage B: [64][264] (odd stride): elu out -> OS input
  __shared__ __align__(16) u16 Xb[16896];
  // Hraw: f32 bounce [32][260] (33.3KB, 2 passes) / H1-half [64][256] swz / resid+LN [64][264]
  __shared__ __align__(16) unsigned char Hraw[33792];
  __shared__ float par[2308];
  u16* Hb = (u16*)Hraw;
  float* Hf = (float*)Hraw;

  float* pb0 = par;          // 512
  float* pb1 = par + 512;    // 256
  float* pg  = par + 768;    // 256
  float* pbt = par + 1024;   // 256
  float* pb2 = par + 1280;   // 256
  float* pW3 = par + 1536;   // 768
  float* pb3 = par + 2304;   // 4

  const int t  = blockIdx.y;        // 0..512
  const int R0 = blockIdx.x * 64;   // row base
  const int tid = threadIdx.x;
  const int lane = tid & 63, w = tid >> 6;
  const int lg = lane >> 4, ll = lane & 15;

  pb0[tid] = b0[tid];
  if (tid < 256) { pb1[tid] = b1[tid]; pg[tid] = lng[tid]; pbt[tid] = lnb[tid]; pb2[tid] = b2[tid]; }
  if (tid < 512) pW3[tid] = W3[tid];
  if (tid < 256) pW3[512 + tid] = W3[512 + tid];
  if (tid < 4) pb3[tid] = (tid < 3) ? b3[tid] : 0.f;

  f32x4 z = {0.f, 0.f, 0.f, 0.f};

  // ---- phase 1: KS_pre rows R0..R0+63; wave w -> cols w*32..+31; acc[4][2] ----
  f32x4 acc[4][2];
#pragma unroll
  for (int mi = 0; mi < 4; ++mi)
#pragma unroll
    for (int ni = 0; ni < 2; ++ni) acc[mi][ni] = z;
  {
    const u16* CrevT = ws + OFF_CRT;
    bf16x8 au[4][2];
#pragma unroll
    for (int mi = 0; mi < 4; ++mi)
#pragma unroll
      for (int ksu = 0; ksu < 2; ++ksu) {
        const u16* up = ws + OFF_UPAD + (R0 + mi * 16 + ll) * 576 + t + ksu * 32 + lg * 8;
#pragma unroll
        for (int e = 0; e < 8; ++e) au[mi][ksu][e] = (short)up[e];
      }
#pragma unroll
    for (int ksu = 0; ksu < 2; ++ksu)
#pragma unroll
      for (int ni = 0; ni < 2; ++ni) {
        int n = w * 32 + ni * 16 + ll;
        bf16x8 bfr = *(const bf16x8*)(CrevT + n * 64 + ksu * 32 + lg * 8);
#pragma unroll
        for (int mi = 0; mi < 4; ++mi) acc[mi][ni] = MFMA16(au[mi][ksu], bfr, acc[mi][ni]);
      }
    if (t < 64) {
      const u16* Pt = ws + OFF_P + t * 65536;
      const u16* ks0b = ws + OFF_KS0;
#pragma unroll
      for (int ks = 0; ks < 8; ++ks) {
        bf16x8 a[4], b[2];
#pragma unroll
        for (int mi = 0; mi < 4; ++mi)
          a[mi] = *(const bf16x8*)(ks0b + (R0 + mi * 16 + ll) * 256 + ks * 32 + lg * 8);
#pragma unroll
        for (int ni = 0; ni < 2; ++ni)
          b[ni] = *(const bf16x8*)(Pt + (w * 32 + ni * 16 + ll) * 256 + ks * 32 + lg * 8);
#pragma unroll
        for (int mi = 0; mi < 4; ++mi)
#pragma unroll
          for (int ni = 0; ni < 2; ++ni) acc[mi][ni] = MFMA16(a[mi], b[ni], acc[mi][ni]);
      }
    }
  }
  __syncthreads();  // params staged; Hraw free for bounce

  // ---- KS store via f32 bounce, 2 passes of 32 rows; Xb built alongside ----
#pragma unroll 1
  for (int p = 0; p < 2; ++p) {
#pragma unroll
    for (int mi2 = 0; mi2 < 2; ++mi2) {
      int mi = p * 2 + mi2;
#pragma unroll
      for (int ni = 0; ni < 2; ++ni)
#pragma unroll
        for (int r = 0; r < 4; ++r)
          Hf[(mi2 * 16 + lg * 4 + r) * 260 + w * 32 + ni * 16 + ll] = acc[mi][ni][r];
    }
    __syncthreads();
    float* ob = out + (size_t)t * 262144 + (size_t)(R0 + p * 32) * 256;
#pragma unroll
    for (int it = 0; it < 4; ++it) {
      int idx = it * 512 + tid;
      int row = idx >> 6, c4 = idx & 63;
      f32x4 v = *(const f32x4*)(Hf + row * 260 + c4 * 4);
      *(f32x4*)(ob + row * 256 + c4 * 4) = v;
      int rl = p * 32 + row;
      bf16x4 h;
#pragma unroll
      for (int e = 0; e < 4; ++e) h[e] = (short)f2bf(v[e]);
      int byt = (((rl << 9) + ((c4 >> 1) << 4)) ^ ((rl & 7) << 4)) + ((c4 & 1) << 3);
      *(bf16x4*)(Xb + (byt >> 1)) = h;
    }
    __syncthreads();
  }

  // ---- L1 + L2 interleaved over two 256-col halves; accL2 persists ----
  const u16* W0b = ws + OFF_W0;
  const u16* W1b = ws + OFF_W1;
  f32x4 accL2[4][2];
#pragma unroll
  for (int mi = 0; mi < 4; ++mi)
#pragma unroll
    for (int ni = 0; ni < 2; ++ni) accL2[mi][ni] = z;

#pragma unroll 1
  for (int h = 0; h < 2; ++h) {
#pragma unroll
    for (int mi = 0; mi < 4; ++mi)
#pragma unroll
      for (int ni = 0; ni < 2; ++ni) acc[mi][ni] = z;
    // L1 GEMM: X (Xb swz) @ W0[h-half]^T
#pragma unroll
    for (int ks = 0; ks < 8; ++ks) {
      bf16x8 a[4], b[2];
#pragma unroll
      for (int mi = 0; mi < 4; ++mi) {
        int rl = mi * 16 + ll;
        int byt = ((rl << 9) + ks * 64 + (lg << 4)) ^ ((rl & 7) << 4);
        a[mi] = *(const bf16x8*)(Xb + (byt >> 1));
      }
#pragma unroll
      for (int ni = 0; ni < 2; ++ni) {
        int n = h * 256 + w * 32 + ni * 16 + ll;
        b[ni] = *(const bf16x8*)(W0b + n * 256 + ks * 32 + lg * 8);
      }
#pragma unroll
      for (int mi = 0; mi < 4; ++mi)
#pragma unroll
        for (int ni = 0; ni < 2; ++ni) acc[mi][ni] = MFMA16(a[mi], b[ni], acc[mi][ni]);
    }
    // act: tanh -> Hb as H-half [64][256] swz (512B stride)
#pragma unroll
    for (int mi = 0; mi < 4; ++mi)
#pragma unroll
      for (int ni = 0; ni < 2; ++ni)
#pragma unroll
        for (int r = 0; r < 4; ++r) {
          int rl = mi * 16 + lg * 4 + r;
          int col_l = w * 32 + ni * 16 + ll;
          float v = fast_tanh(acc[mi][ni][r] + pb0[h * 256 + col_l]);
          int byt = ((rl << 9) + (col_l << 1)) ^ ((rl & 7) << 4);
          Hb[byt >> 1] = f2bf(v);
        }
    __syncthreads();
    // L2 partial: H-half @ W1[:, h*256:+256]^T
#pragma unroll
    for (int ks = 0; ks < 8; ++ks) {
      bf16x8 a[4], b[2];
#pragma unroll
      for (int mi = 0; mi < 4; ++mi) {
        int rl = mi * 16 + ll;
        int byt = ((rl << 9) + ks * 64 + (lg << 4)) ^ ((rl & 7) << 4);
        a[mi] = *(const bf16x8*)(Hb + (byt >> 1));
      }
#pragma unroll
      for (int ni = 0; ni < 2; ++ni) {
        int n = w * 32 + ni * 16 + ll;
        b[ni] = *(const bf16x8*)(W1b + n * 512 + h * 256 + ks * 32 + lg * 8);
      }
#pragma unroll
      for (int mi = 0; mi < 4; ++mi)
#pragma unroll
        for (int ni = 0; ni < 2; ++ni) accL2[mi][ni] = MFMA16(a[mi], b[ni], accL2[mi][ni]);
    }
    __syncthreads();
  }

  // ---- residual: r = X + tanh(accL2 + b1) -> Hb [64][264] (odd stride) ----
#pragma unroll
  for (int mi = 0; mi < 4; ++mi)
#pragma unroll
    for (int ni = 0; ni < 2; ++ni)
#pragma unroll
      for (int r = 0; r < 4; ++r) {
        int rl = mi * 16 + lg * 4 + r;
        int col = w * 32 + ni * 16 + ll;
        float v = fast_tanh(accL2[mi][ni][r] + pb1[col]);
        int bx = ((rl << 9) + (col << 1)) ^ ((rl & 7) << 4);
        v += bf2f(Xb[bx >> 1]);
        Hb[rl * 264 + col] = f2bf(v);
      }
  __syncthreads();

  // ---- LayerNorm per row, in place ([64][264]); 8 lanes per row ----
  {
    int row = tid >> 3, jq = tid & 7;
    u16* hr = Hb + row * 264 + jq * 32;
    bf16x8 chv[4];
#pragma unroll
    for (int q = 0; q < 4; ++q) chv[q] = *(const bf16x8*)(hr + q * 8);
    float s = 0.f, ss = 0.f;
#pragma unroll
    for (int q = 0; q < 4; ++q)
#pragma unroll
      for (int e = 0; e < 8; ++e) { float v = bf2f((u16)chv[q][e]); s += v; ss += v * v; }
    s += __shfl_xor(s, 1);  s += __shfl_xor(s, 2);  s += __shfl_xor(s, 4);
    ss += __shfl_xor(ss, 1); ss += __shfl_xor(ss, 2); ss += __shfl_xor(ss, 4);
    float mu = s * 0.00390625f;
    float var = ss * 0.00390625f - mu * mu;
    float rstd = rsqrtf(var + 1e-5f);
#pragma unroll
    for (int q = 0; q < 4; ++q) {
      bf16x8 o;
#pragma unroll
      for (int e = 0; e < 8; ++e) {
        int col = jq * 32 + q * 8 + e;
        float v = (bf2f((u16)chv[q][e]) - mu) * rstd * pg[col] + pbt[col];
        o[e] = (short)f2bf(v);
      }
      *(bf16x8*)(hr + q * 8) = o;
    }
  }
  __syncthreads();

  // ---- L3: elu(s2n @ W2^T + b2) -> Xb [64][264] ----
#pragma unroll
  for (int mi = 0; mi < 4; ++mi)
#pragma unroll
    for (int ni = 0; ni < 2; ++ni) acc[mi][ni] = z;
  {
    const u16* W2b = ws + OFF_W2;
#pragma unroll
    for (int ks = 0; ks < 8; ++ks) {
      bf16x8 a[4], b[2];
#pragma unroll
      for (int mi = 0; mi < 4; ++mi) {
        int rl = mi * 16 + ll;
        a[mi] = *(const bf16x8*)(Hb + rl * 264 + ks * 32 + lg * 8);
      }
#pragma unroll
      for (int ni = 0; ni < 2; ++ni) {
        int n = w * 32 + ni * 16 + ll;
        b[ni] = *(const bf16x8*)(W2b + n * 256 + ks * 32 + lg * 8);
      }
#pragma unroll
      for (int mi = 0; mi < 4; ++mi)
#pragma unroll
        for (int ni = 0; ni < 2; ++ni) acc[mi][ni] = MFMA16(a[mi], b[ni], acc[mi][ni]);
    }
  }
#pragma unroll
  for (int mi = 0; mi < 4; ++mi)
#pragma unroll
    for (int ni = 0; ni < 2; ++ni)
#pragma unroll
      for (int r = 0; r < 4; ++r) {
        int rl = mi * 16 + lg * 4 + r;
        int col = w * 32 + ni * 16 + ll;
        float v = acc[mi][ni][r] + pb2[col];
        v = v > 0.f ? v : (__expf(v) - 1.f);
        Xb[rl * 264 + col] = f2bf(v);
      }
  __syncthreads();

  // ---- OS = H3 @ W3^T + b3 ; 8 lanes per row ----
  {
    int row = tid >> 3, jq = tid & 7;
    const u16* xr = Xb + row * 264 + jq * 32;
    float d0 = 0.f, d1 = 0.f, d2 = 0.f;
#pragma unroll
    for (int q = 0; q < 4; ++q) {
      bf16x8 c = *(const bf16x8*)(xr + q * 8);
#pragma unroll
      for (int e = 0; e < 8; ++e) {
        float v = bf2f((u16)c[e]);
        int col = jq * 32 + q * 8 + e;
        d0 += v * pW3[col]; d1 += v * pW3[256 + col]; d2 += v * pW3[512 + col];
      }
    }
    d0 += __shfl_xor(d0, 1); d0 += __shfl_xor(d0, 2); d0 += __shfl_xor(d0, 4);
    d1 += __shfl_xor(d1, 1); d1 += __shfl_xor(d1, 2); d1 += __shfl_xor(d1, 4);
    d2 += __shfl_xor(d2, 1); d2 += __shfl_xor(d2, 2); d2 += __shfl_xor(d2, 4);
    if (jq == 0) {
      int grow = R0 + row;
      int ob = OS_OFF + t * 3072 + grow * 3;
      out[ob]     = d0 + pb3[0];
      out[ob + 1] = d1 + pb3[1];
      out[ob + 2] = d2 + pb3[2];
    }
  }
}

extern "C" void kernel_launch(void* const* d_in, const int* in_sizes, int n_in,
                              void* d_out, int out_size, void* d_ws, size_t ws_size,
                              hipStream_t stream) {
  const float* KS_ALL  = (const float*)d_in[0];
  const float* next_vf = (const float*)d_in[1];
  const float* A_w     = (const float*)d_in[2];
  const float* B_w     = (const float*)d_in[3];
  const float* W0      = (const float*)d_in[4];
  const float* b0      = (const float*)d_in[5];
  const float* W1      = (const float*)d_in[6];
  const float* b1      = (const float*)d_in[7];
  const float* lng     = (const float*)d_in[8];
  const float* lnb     = (const float*)d_in[9];
  const float* W2      = (const float*)d_in[10];
  const float* b2      = (const float*)d_in[11];
  const float* W3      = (const float*)d_in[12];
  const float* b3      = (const float*)d_in[13];
  u16* ws = (u16*)d_ws;
  float* out = (float*)d_out;

  k_prep<<<4864, 256, 0, stream>>>(KS_ALL, next_vf, A_w, W0, W1, W2, ws);
  for (int s = 1; s <= 32; s <<= 1)
    k_pow<<<dim3(2, s), 512, 0, stream>>>(ws, s);
  k_crevt<<<64, 256, 0, stream>>>(B_w, ws);
  k_fused<<<dim3(16, 513), 512, 0, stream>>>(ws, b0, b1, lng, lnb, b2, W3, b3, out);
}